// Round 2
// baseline (1427.414 us; speedup 1.0000x reference)
//
#include <hip/hip_runtime.h>
#include <hip/hip_bf16.h>
#include <math.h>

#define B_ 4
#define C_ 512
#define N_ 4096

typedef float f32x4 __attribute__((ext_vector_type(4)));
typedef __bf16 bf16x8 __attribute__((ext_vector_type(8)));

#define AS1(p) ((const __attribute__((address_space(1))) unsigned int*)(p))
#define AS3(p) ((__attribute__((address_space(3))) unsigned int*)(p))

__device__ __forceinline__ unsigned short f2bf(float x){
    unsigned u = __builtin_bit_cast(unsigned, x);
    return (unsigned short)((u + 0x7FFFu + ((u>>16)&1u)) >> 16);
}
__device__ __forceinline__ float bf2f(unsigned short b){
    unsigned u = ((unsigned)b)<<16;
    return __builtin_bit_cast(float, u);
}
__device__ __forceinline__ f32x4 mfma16(bf16x8 a, bf16x8 b, f32x4 c){
    return __builtin_amdgcn_mfma_f32_16x16x32_bf16(a, b, c, 0, 0, 0);
}

// ---------------- weight fp32 -> bf16 hi/lo split ----------------
__global__ void split_w(const float* __restrict__ src, unsigned short* __restrict__ hi,
                        unsigned short* __restrict__ lo){
    const int i = (blockIdx.x*256 + threadIdx.x)*4;
    f32x4 v = *(const f32x4*)(src + i);
    ushort4 h, l;
    unsigned short t0=f2bf(v[0]); h.x=t0; l.x=f2bf(v[0]-bf2f(t0));
    unsigned short t1=f2bf(v[1]); h.y=t1; l.y=f2bf(v[1]-bf2f(t1));
    unsigned short t2=f2bf(v[2]); h.z=t2; l.z=f2bf(v[2]-bf2f(t2));
    unsigned short t3=f2bf(v[3]); h.w=t3; l.w=f2bf(v[3]-bf2f(t3));
    *(ushort4*)(hi + i) = h;
    *(ushort4*)(lo + i) = l;
}

// ---------------- GroupNorm: partial sums ----------------
__global__ void gn_part(const float* __restrict__ x, float2* __restrict__ part){
    const int bg = blockIdx.y, blk = blockIdx.x, t = threadIdx.x;
    const float* base = x + (size_t)bg*(256*4096) + (size_t)blk*16384;
    float s = 0.f, q = 0.f;
    for (int i=0;i<16;i++){
        f32x4 v = *(const f32x4*)(base + i*1024 + t*4);
        s += v[0]+v[1]+v[2]+v[3];
        q += v[0]*v[0]+v[1]*v[1]+v[2]*v[2]+v[3]*v[3];
    }
    #pragma unroll
    for (int o=32;o>0;o>>=1){ s += __shfl_down(s, o); q += __shfl_down(q, o); }
    __shared__ float as[4], aq[4];
    if ((t&63)==0){ as[t>>6]=s; aq[t>>6]=q; }
    __syncthreads();
    if (t==0)
        part[bg*64 + blk] = make_float2(as[0]+as[1]+as[2]+as[3], aq[0]+aq[1]+aq[2]+aq[3]);
}

__global__ void gn_fin(const float2* __restrict__ part, float2* __restrict__ stats){
    const int bg = blockIdx.x, t = threadIdx.x;
    float2 p = part[bg*64 + t];
    float s = p.x, q = p.y;
    #pragma unroll
    for (int o=32;o>0;o>>=1){ s += __shfl_down(s,o); q += __shfl_down(q,o); }
    if (t==0){
        const float inv = 1.0f/(256.f*4096.f);
        float mu = s*inv;
        float var = q*inv - mu*mu;
        stats[bg] = make_float2(mu, rsqrtf(var + 1e-6f));
    }
}

// ---- GN apply + transpose + hi/lo split: x[B][C][N] -> hT[B][N][C] (bf16 hi,lo) ----
__global__ void gn_apply(const float* __restrict__ x, const float* __restrict__ gw,
                         const float* __restrict__ gb, const float2* __restrict__ stats,
                         unsigned short* __restrict__ hTh, unsigned short* __restrict__ hTl)
{
    const int b = blockIdx.z, c0 = blockIdx.y*32, n0 = blockIdx.x*32;
    const int t = threadIdx.x;
    __shared__ float tile[32][37];
    {
        const int cl = t>>3, nl = (t&7)*4;
        const int c = c0 + cl;
        const float2 st = stats[b*2 + (c>>8)];
        const float wv = gw[c], bvv = gb[c];
        const f32x4 v = *(const f32x4*)(x + ((size_t)b*C_ + c)*N_ + n0 + nl);
        #pragma unroll
        for (int i=0;i<4;i++) tile[cl][nl+i] = (v[i] - st.x)*st.y*wv + bvv;
    }
    __syncthreads();
    {
        const int nl = t>>3, cl = (t&7)*4;
        const int n = n0 + nl;
        float f0 = tile[cl+0][nl], f1 = tile[cl+1][nl], f2 = tile[cl+2][nl], f3 = tile[cl+3][nl];
        unsigned short h0=f2bf(f0), h1=f2bf(f1), h2=f2bf(f2), h3=f2bf(f3);
        ushort4 hh, ll;
        hh.x=h0; hh.y=h1; hh.z=h2; hh.w=h3;
        ll.x=f2bf(f0-bf2f(h0)); ll.y=f2bf(f1-bf2f(h1));
        ll.z=f2bf(f2-bf2f(h2)); ll.w=f2bf(f3-bf2f(h3));
        size_t o = ((size_t)b*N_ + n)*C_ + c0 + cl;
        *(ushort4*)(hTh + o) = hh;
        *(ushort4*)(hTl + o) = ll;
    }
}

// ---------------- conv GEMM: out[o,n] = sum_c W[o,c]*S[c,n] + bias[o] ----------------
template<int PROD, int MODE>
__global__ __launch_bounds__(256, 2) void conv_gemm(
    const unsigned short* __restrict__ Wh, const unsigned short* __restrict__ Wl,
    const unsigned short* __restrict__ Sh, const unsigned short* __restrict__ Sl,
    const float* __restrict__ bias,
    unsigned short* __restrict__ outHi, unsigned short* __restrict__ outLo,
    float* __restrict__ outF, const float* __restrict__ resid)
{
    const int b = blockIdx.z, o0 = blockIdx.y*128, n0 = blockIdx.x*128;
    const int t = threadIdx.x, w = t>>6, l = t&63, lr = l&15, lg = l>>4;
    const int ro = (w>>1)*64, co = (w&1)*64;
    __shared__ unsigned short Ah[128][40];
    __shared__ unsigned short Al[128][40];
    __shared__ unsigned short Bh[128][40];
    __shared__ unsigned short Bl[128][40];
    f32x4 acc[4][4];
    #pragma unroll
    for (int i=0;i<4;i++)
        #pragma unroll
        for (int j=0;j<4;j++) acc[i][j] = (f32x4){0.f,0.f,0.f,0.f};

    const size_t srcB = (size_t)b*N_*C_;
    for (int ks=0; ks<16; ks++){
        const int c0 = ks*32;
        #pragma unroll
        for (int i=0;i<2;i++){
            int u = t + i*256;
            int row = u>>2, sch = (u&3)*8;
            *(bf16x8*)&Ah[row][sch] = *(const bf16x8*)(Wh + (size_t)(o0+row)*C_ + c0 + sch);
            *(bf16x8*)&Bh[row][sch] = *(const bf16x8*)(Sh + srcB + (size_t)(n0+row)*C_ + c0 + sch);
            if constexpr (PROD==3){
                *(bf16x8*)&Al[row][sch] = *(const bf16x8*)(Wl + (size_t)(o0+row)*C_ + c0 + sch);
                *(bf16x8*)&Bl[row][sch] = *(const bf16x8*)(Sl + srcB + (size_t)(n0+row)*C_ + c0 + sch);
            }
        }
        __syncthreads();
        bf16x8 af[4], bfv[4], afl[4], bfl[4];
        #pragma unroll
        for (int i=0;i<4;i++){
            af[i]  = *(const bf16x8*)&Ah[ro + i*16 + lr][lg*8];
            bfv[i] = *(const bf16x8*)&Bh[co + i*16 + lr][lg*8];
            if constexpr (PROD==3){
                afl[i] = *(const bf16x8*)&Al[ro + i*16 + lr][lg*8];
                bfl[i] = *(const bf16x8*)&Bl[co + i*16 + lr][lg*8];
            }
        }
        #pragma unroll
        for (int i=0;i<4;i++)
            #pragma unroll
            for (int j=0;j<4;j++){
                acc[i][j] = mfma16(af[i], bfv[j], acc[i][j]);
                if constexpr (PROD==3){
                    acc[i][j] = mfma16(af[i],  bfl[j], acc[i][j]);
                    acc[i][j] = mfma16(afl[i], bfv[j], acc[i][j]);
                }
            }
        __syncthreads();
    }
    #pragma unroll
    for (int i=0;i<4;i++){
        const int ob = o0 + ro + i*16 + lg*4;
        #pragma unroll
        for (int j=0;j<4;j++){
            const int n = n0 + co + j*16 + lr;
            f32x4 v = acc[i][j];
            if constexpr (MODE==0){
                float v0 = v[0] + bias[ob+0]; unsigned short h0 = f2bf(v0);
                float v1 = v[1] + bias[ob+1]; unsigned short h1 = f2bf(v1);
                float v2 = v[2] + bias[ob+2]; unsigned short h2 = f2bf(v2);
                float v3 = v[3] + bias[ob+3]; unsigned short h3 = f2bf(v3);
                ushort4 hh, ll;
                hh.x=h0; hh.y=h1; hh.z=h2; hh.w=h3;
                ll.x=f2bf(v0-bf2f(h0)); ll.y=f2bf(v1-bf2f(h1));
                ll.z=f2bf(v2-bf2f(h2)); ll.w=f2bf(v3-bf2f(h3));
                *(ushort4*)(outHi + srcB + (size_t)n*C_ + ob) = hh;
                *(ushort4*)(outLo + srcB + (size_t)n*C_ + ob) = ll;
            } else if constexpr (MODE==1){
                #pragma unroll
                for (int r=0;r<4;r++)
                    outHi[((size_t)b*C_ + ob + r)*N_ + n] = f2bf(v[r] + bias[ob+r]);
            } else {
                #pragma unroll
                for (int r=0;r<4;r++){
                    size_t idx = ((size_t)b*C_ + ob + r)*N_ + n;
                    outF[idx] = resid[idx] + v[r] + bias[ob+r];
                }
            }
        }
    }
}

// ---------------- flash attention, split-m, 32 q-rows/block ----------------
// grid (128 n-blocks, 2 m-splits, B). 8 waves: fm(2) x fn(2) x ch(2) for QK,
// nf(2) x cgroup(4) for PV. K staged via global_load_lds w/ pre-swizzled src.
// Writes UNNORMALIZED partial O (bf16) + per-row (m, s) for the combine pass.
__global__ __launch_bounds__(512, 4) void attn_flash2(
    const unsigned short* __restrict__ qTh, const unsigned short* __restrict__ qTl,
    const unsigned short* __restrict__ kTh, const unsigned short* __restrict__ kTl,
    const unsigned short* __restrict__ vB,
    unsigned short* __restrict__ Of, float2* __restrict__ Ms)
{
    const int b = blockIdx.z, split = blockIdx.y, n0 = blockIdx.x*32;
    const int t = threadIdx.x, w = t>>6, l = t&63, lr = l&15, lg = l>>4;
    const int fm = (w>>2)&1, fn = (w>>1)&1, ch = w&1;
    const int nf = w>>2, cbase = (w&3)*128;
    const int mstart = split*2048;

    __shared__ unsigned short kh[32*512];
    __shared__ unsigned short kl[32*512];
    __shared__ float Sb[2][32][33];
    __shared__ __align__(16) unsigned short Pb[32][40];
    __shared__ float rowM[32], rowS[32], rowF[32];

    // q fragments for this wave: rows n0+fm*16+lr, c-half ch (256 ch)
    bf16x8 qh[8], ql[8];
    {
        const size_t qr = ((size_t)b*N_ + n0 + fm*16 + lr)*C_ + ch*256;
        #pragma unroll
        for (int kc=0; kc<8; kc++){
            qh[kc] = *(const bf16x8*)(qTh + qr + kc*32 + lg*8);
            ql[kc] = *(const bf16x8*)(qTl + qr + kc*32 + lg*8);
        }
    }
    f32x4 acc[8];
    #pragma unroll
    for (int i=0;i<8;i++) acc[i] = (f32x4){0.f,0.f,0.f,0.f};
    if (t < 32){ rowM[t] = -INFINITY; rowS[t] = 0.f; }

    const size_t kTileBytes0 = (size_t)(b*N_ + mstart)*1024;   // C_*2 bytes per row

    // async stage of K tile mt (pre-swizzled global source -> linear LDS dest)
    auto stage = [&](int mt){
        const size_t kb = kTileBytes0 + (size_t)mt*32*1024;
        #pragma unroll
        for (int i=0;i<4;i++){
            const int d = i*8192 + t*16;
            const int row = i*8 + w;
            const int colb = (l*16) ^ ((row&7)<<4);
            const size_t g = kb + (size_t)row*1024 + colb;
            __builtin_amdgcn_global_load_lds(AS1((const char*)kTh + g), AS3((char*)kh + d), 16, 0, 0);
            __builtin_amdgcn_global_load_lds(AS1((const char*)kTl + g), AS3((char*)kl + d), 16, 0, 0);
        }
    };

    stage(0);
    __syncthreads();

    for (int mt=0; mt<64; mt++){
        // ---- QK^T partial (this wave: rows fm, cols fn, c-half ch) ----
        f32x4 s0 = (f32x4){0.f,0.f,0.f,0.f}, s1 = s0, s2 = s0;
        {
            const int krow = fn*16 + lr;
            const int rbase = krow*1024;
            const int swz = (krow&7)<<4;
            #pragma unroll
            for (int kc=0;kc<8;kc++){
                const int o = rbase + ((ch*512 + kc*64 + lg*16) ^ swz);
                bf16x8 kf  = *(const bf16x8*)((const char*)kh + o);
                bf16x8 kfl = *(const bf16x8*)((const char*)kl + o);
                s0 = mfma16(qh[kc], kf,  s0);
                s1 = mfma16(qh[kc], kfl, s1);
                s2 = mfma16(ql[kc], kf,  s2);
            }
        }
        #pragma unroll
        for (int r=0;r<4;r++)
            Sb[ch][fm*16 + lg*4 + r][fn*16 + lr] = s0[r]+s1[r]+s2[r];
        __syncthreads();

        // issue async K stage for next tile (overlaps softmax + PV)
        if (mt < 63) stage(mt+1);

        // ---- online softmax: 16 threads/row, 2 cols each ----
        {
            const int row = t>>4, j = t&15;
            float a0 = (Sb[0][row][j*2+0] + Sb[1][row][j*2+0])*22.62741699796952f;
            float a1 = (Sb[0][row][j*2+1] + Sb[1][row][j*2+1])*22.62741699796952f;
            float mx = fmaxf(a0, a1);
            mx = fmaxf(mx, __shfl_xor(mx, 1, 16));
            mx = fmaxf(mx, __shfl_xor(mx, 2, 16));
            mx = fmaxf(mx, __shfl_xor(mx, 4, 16));
            mx = fmaxf(mx, __shfl_xor(mx, 8, 16));
            const float mprev = rowM[row];
            const float mnew = fmaxf(mprev, mx);
            float p0 = __expf(a0 - mnew), p1 = __expf(a1 - mnew);
            float ps = p0 + p1;
            ps += __shfl_xor(ps, 1, 16);
            ps += __shfl_xor(ps, 2, 16);
            ps += __shfl_xor(ps, 4, 16);
            ps += __shfl_xor(ps, 8, 16);
            ushort2 pk; pk.x = f2bf(p0); pk.y = f2bf(p1);
            *(ushort2*)&Pb[row][j*2] = pk;
            if (j==0){
                float f = __expf(mprev - mnew);
                rowF[row] = f;
                rowS[row] = rowS[row]*f + ps;
                rowM[row] = mnew;
            }
        }
        __syncthreads();

        // ---- rescale + PV ----
        float fr[4];
        #pragma unroll
        for (int r=0;r<4;r++) fr[r] = rowF[nf*16 + lg*4 + r];
        #pragma unroll
        for (int cf=0;cf<8;cf++)
            #pragma unroll
            for (int r=0;r<4;r++) acc[cf][r] *= fr[r];

        bf16x8 pa = *(const bf16x8*)&Pb[nf*16 + lr][lg*8];
        const size_t vcol = (size_t)(mstart + mt*32 + lg*8);
        #pragma unroll
        for (int g2=0; g2<2; g2++){
            bf16x8 vf[4];
            #pragma unroll
            for (int u=0;u<4;u++){
                const int cf = g2*4 + u;
                vf[u] = *(const bf16x8*)(vB + ((size_t)b*C_ + cbase + cf*16 + lr)*N_ + vcol);
            }
            #pragma unroll
            for (int u=0;u<4;u++)
                acc[g2*4+u] = mfma16(pa, vf[u], acc[g2*4+u]);
        }
        __syncthreads();
    }

    // ---- write unnormalized partial O (bf16) + (m,s) ----
    const size_t ob = (((size_t)split*B_ + b)*N_ + n0 + nf*16)*C_ + cbase;
    #pragma unroll
    for (int cf=0;cf<8;cf++)
        #pragma unroll
        for (int r=0;r<4;r++)
            Of[ob + (size_t)(lg*4 + r)*C_ + cf*16 + lr] = f2bf(acc[cf][r]);
    if (t < 32){
        Ms[((size_t)split*B_ + b)*N_ + n0 + t] = make_float2(rowM[t], rowS[t]);
    }
}

// ---------------- combine the 2 m-splits ----------------
__global__ void attn_combine(const unsigned short* __restrict__ Of, const float2* __restrict__ Ms,
                             unsigned short* __restrict__ ao)
{
    const size_t e = ((size_t)blockIdx.x*256 + threadIdx.x)*8;
    const size_t bn = e >> 9;
    const size_t NC = (size_t)B_*N_*C_;
    const float2 s0 = Ms[bn], s1 = Ms[(size_t)B_*N_ + bn];
    const float M = fmaxf(s0.x, s1.x);
    const float w0 = __expf(s0.x - M), w1 = __expf(s1.x - M);
    const float inv = 1.0f/(s0.y*w0 + s1.y*w1);
    const float a = w0*inv, c = w1*inv;
    ushort4 x0 = *(const ushort4*)(Of + e),      x1 = *(const ushort4*)(Of + e + 4);
    ushort4 y0 = *(const ushort4*)(Of + NC + e), y1 = *(const ushort4*)(Of + NC + e + 4);
    ushort4 r0, r1;
    r0.x = f2bf(bf2f(x0.x)*a + bf2f(y0.x)*c);
    r0.y = f2bf(bf2f(x0.y)*a + bf2f(y0.y)*c);
    r0.z = f2bf(bf2f(x0.z)*a + bf2f(y0.z)*c);
    r0.w = f2bf(bf2f(x0.w)*a + bf2f(y0.w)*c);
    r1.x = f2bf(bf2f(x1.x)*a + bf2f(y1.x)*c);
    r1.y = f2bf(bf2f(x1.y)*a + bf2f(y1.y)*c);
    r1.z = f2bf(bf2f(x1.z)*a + bf2f(y1.z)*c);
    r1.w = f2bf(bf2f(x1.w)*a + bf2f(y1.w)*c);
    *(ushort4*)(ao + e)     = r0;
    *(ushort4*)(ao + e + 4) = r1;
}

extern "C" void kernel_launch(void* const* d_in, const int* in_sizes, int n_in,
                              void* d_out, int out_size, void* d_ws, size_t ws_size,
                              hipStream_t stream)
{
    const float* x   = (const float*)d_in[0];
    const float* gnw = (const float*)d_in[1];
    const float* gnb = (const float*)d_in[2];
    const float* wq  = (const float*)d_in[3];
    const float* bq  = (const float*)d_in[4];
    const float* wk  = (const float*)d_in[5];
    const float* bk  = (const float*)d_in[6];
    const float* wv  = (const float*)d_in[7];
    const float* bv  = (const float*)d_in[8];
    const float* wp  = (const float*)d_in[9];
    const float* bp  = (const float*)d_in[10];
    float* out = (float*)d_out;

    char* ws = (char*)d_ws;
    size_t off = 0;
    auto alloc = [&](size_t bytes)->char*{
        char* p = ws + off; off += (bytes + 255) & ~(size_t)255; return p;
    };
    const size_t WB = (size_t)C_*C_*2;
    const size_t TB = (size_t)B_*N_*C_*2;
    unsigned short* wqh = (unsigned short*)alloc(WB);
    unsigned short* wql = (unsigned short*)alloc(WB);
    unsigned short* wkh = (unsigned short*)alloc(WB);
    unsigned short* wkl = (unsigned short*)alloc(WB);
    unsigned short* wvh = (unsigned short*)alloc(WB);
    unsigned short* wvl = (unsigned short*)alloc(WB);
    unsigned short* wph = (unsigned short*)alloc(WB);
    unsigned short* wpl = (unsigned short*)alloc(WB);
    unsigned short* hTh = (unsigned short*)alloc(TB);
    unsigned short* hTl = (unsigned short*)alloc(TB);   // hTh..hTl contiguous: reused as Of[2] (2*TB)
    unsigned short* qTh = (unsigned short*)alloc(TB);
    unsigned short* qTl = (unsigned short*)alloc(TB);
    unsigned short* kTh = (unsigned short*)alloc(TB);
    unsigned short* kTl = (unsigned short*)alloc(TB);
    unsigned short* vb  = (unsigned short*)alloc(TB);
    unsigned short* ao  = (unsigned short*)alloc(TB);
    float2* part  = (float2*)alloc(8*64*sizeof(float2));
    float2* stats = (float2*)alloc(8*sizeof(float2));
    float2* Ms    = (float2*)alloc((size_t)2*B_*N_*sizeof(float2));
    unsigned short* Of = hTh;   // [2][B][N][C] bf16, overlays dead hTh+hTl

    split_w<<<256, 256, 0, stream>>>(wq, wqh, wql);
    split_w<<<256, 256, 0, stream>>>(wk, wkh, wkl);
    split_w<<<256, 256, 0, stream>>>(wv, wvh, wvl);
    split_w<<<256, 256, 0, stream>>>(wp, wph, wpl);
    gn_part<<<dim3(64, 8), 256, 0, stream>>>(x, part);
    gn_fin<<<8, 64, 0, stream>>>(part, stats);
    gn_apply<<<dim3(128, 16, B_), 256, 0, stream>>>(x, gnw, gnb, stats, hTh, hTl);
    conv_gemm<3,0><<<dim3(32,4,B_), 256, 0, stream>>>(wqh,wql,hTh,hTl,bq, qTh,qTl,nullptr,nullptr);
    conv_gemm<3,0><<<dim3(32,4,B_), 256, 0, stream>>>(wkh,wkl,hTh,hTl,bk, kTh,kTl,nullptr,nullptr);
    conv_gemm<1,1><<<dim3(32,4,B_), 256, 0, stream>>>(wvh,wvl,hTh,hTl,bv, vb,nullptr,nullptr,nullptr);
    attn_flash2<<<dim3(128, 2, B_), 512, 0, stream>>>(qTh,qTl,kTh,kTl,vb, Of, Ms);
    attn_combine<<<4096, 256, 0, stream>>>(Of, Ms, ao);
    conv_gemm<1,2><<<dim3(32,4,B_), 256, 0, stream>>>(wph,wpl,ao,nullptr,bp, nullptr,nullptr,out,x);
}

// Round 3
// 542.314 us; speedup vs baseline: 2.6321x; 2.6321x over previous
//
#include <hip/hip_runtime.h>
#include <hip/hip_bf16.h>
#include <math.h>

#define B_ 4
#define C_ 512
#define N_ 4096

typedef float f32x4 __attribute__((ext_vector_type(4)));
typedef __bf16 bf16x8 __attribute__((ext_vector_type(8)));

#define AS1(p) ((const __attribute__((address_space(1))) unsigned int*)(p))
#define AS3(p) ((__attribute__((address_space(3))) unsigned int*)(p))

__device__ __forceinline__ unsigned short f2bf(float x){
    return __builtin_bit_cast(unsigned short, (__bf16)x);
}
__device__ __forceinline__ float bf2f(unsigned short b){
    unsigned u = ((unsigned)b)<<16;
    return __builtin_bit_cast(float, u);
}
__device__ __forceinline__ f32x4 mfma16(bf16x8 a, bf16x8 b, f32x4 c){
    return __builtin_amdgcn_mfma_f32_16x16x32_bf16(a, b, c, 0, 0, 0);
}
__device__ __forceinline__ void bar_lgkm(){
    asm volatile("s_waitcnt lgkmcnt(0)" ::: "memory");
    __builtin_amdgcn_s_barrier();
}
__device__ __forceinline__ void bar_vm(){
    asm volatile("s_waitcnt vmcnt(0)" ::: "memory");
    __builtin_amdgcn_s_barrier();
}

// ---------------- weight fp32 -> bf16 hi/lo split ----------------
__global__ void split_w(const float* __restrict__ src, unsigned short* __restrict__ hi,
                        unsigned short* __restrict__ lo){
    const int i = (blockIdx.x*256 + threadIdx.x)*4;
    f32x4 v = *(const f32x4*)(src + i);
    ushort4 h, l;
    unsigned short t0=f2bf(v[0]); h.x=t0; l.x=f2bf(v[0]-bf2f(t0));
    unsigned short t1=f2bf(v[1]); h.y=t1; l.y=f2bf(v[1]-bf2f(t1));
    unsigned short t2=f2bf(v[2]); h.z=t2; l.z=f2bf(v[2]-bf2f(t2));
    unsigned short t3=f2bf(v[3]); h.w=t3; l.w=f2bf(v[3]-bf2f(t3));
    *(ushort4*)(hi + i) = h;
    *(ushort4*)(lo + i) = l;
}

// ---------------- GroupNorm: partial sums ----------------
__global__ void gn_part(const float* __restrict__ x, float2* __restrict__ part){
    const int bg = blockIdx.y, blk = blockIdx.x, t = threadIdx.x;
    const float* base = x + (size_t)bg*(256*4096) + (size_t)blk*16384;
    float s = 0.f, q = 0.f;
    for (int i=0;i<16;i++){
        f32x4 v = *(const f32x4*)(base + i*1024 + t*4);
        s += v[0]+v[1]+v[2]+v[3];
        q += v[0]*v[0]+v[1]*v[1]+v[2]*v[2]+v[3]*v[3];
    }
    #pragma unroll
    for (int o=32;o>0;o>>=1){ s += __shfl_down(s, o); q += __shfl_down(q, o); }
    __shared__ float as[4], aq[4];
    if ((t&63)==0){ as[t>>6]=s; aq[t>>6]=q; }
    __syncthreads();
    if (t==0)
        part[bg*64 + blk] = make_float2(as[0]+as[1]+as[2]+as[3], aq[0]+aq[1]+aq[2]+aq[3]);
}

__global__ void gn_fin(const float2* __restrict__ part, float2* __restrict__ stats){
    const int bg = blockIdx.x, t = threadIdx.x;
    float2 p = part[bg*64 + t];
    float s = p.x, q = p.y;
    #pragma unroll
    for (int o=32;o>0;o>>=1){ s += __shfl_down(s,o); q += __shfl_down(q,o); }
    if (t==0){
        const float inv = 1.0f/(256.f*4096.f);
        float mu = s*inv;
        float var = q*inv - mu*mu;
        stats[bg] = make_float2(mu, rsqrtf(var + 1e-6f));
    }
}

// ---- GN apply + transpose + hi/lo split: x[B][C][N] -> hT[B][N][C] (bf16 hi,lo) ----
__global__ void gn_apply(const float* __restrict__ x, const float* __restrict__ gw,
                         const float* __restrict__ gb, const float2* __restrict__ stats,
                         unsigned short* __restrict__ hTh, unsigned short* __restrict__ hTl)
{
    const int b = blockIdx.z, c0 = blockIdx.y*32, n0 = blockIdx.x*32;
    const int t = threadIdx.x;
    __shared__ float tile[32][37];
    {
        const int cl = t>>3, nl = (t&7)*4;
        const int c = c0 + cl;
        const float2 st = stats[b*2 + (c>>8)];
        const float wv = gw[c], bvv = gb[c];
        const f32x4 v = *(const f32x4*)(x + ((size_t)b*C_ + c)*N_ + n0 + nl);
        #pragma unroll
        for (int i=0;i<4;i++) tile[cl][nl+i] = (v[i] - st.x)*st.y*wv + bvv;
    }
    __syncthreads();
    {
        const int nl = t>>3, cl = (t&7)*4;
        const int n = n0 + nl;
        float f0 = tile[cl+0][nl], f1 = tile[cl+1][nl], f2 = tile[cl+2][nl], f3 = tile[cl+3][nl];
        unsigned short h0=f2bf(f0), h1=f2bf(f1), h2=f2bf(f2), h3=f2bf(f3);
        ushort4 hh, ll;
        hh.x=h0; hh.y=h1; hh.z=h2; hh.w=h3;
        ll.x=f2bf(f0-bf2f(h0)); ll.y=f2bf(f1-bf2f(h1));
        ll.z=f2bf(f2-bf2f(h2)); ll.w=f2bf(f3-bf2f(h3));
        size_t o = ((size_t)b*N_ + n)*C_ + c0 + cl;
        *(ushort4*)(hTh + o) = hh;
        *(ushort4*)(hTl + o) = ll;
    }
}

// ---------------- conv GEMM: out[o,n] = sum_c W[o,c]*S[c,n] + bias[o] ----------------
template<int PROD, int MODE>
__global__ __launch_bounds__(256, 2) void conv_gemm(
    const unsigned short* __restrict__ Wh, const unsigned short* __restrict__ Wl,
    const unsigned short* __restrict__ Sh, const unsigned short* __restrict__ Sl,
    const float* __restrict__ bias,
    unsigned short* __restrict__ outHi, unsigned short* __restrict__ outLo,
    float* __restrict__ outF, const float* __restrict__ resid)
{
    const int b = blockIdx.z, o0 = blockIdx.y*128, n0 = blockIdx.x*128;
    const int t = threadIdx.x, w = t>>6, l = t&63, lr = l&15, lg = l>>4;
    const int ro = (w>>1)*64, co = (w&1)*64;
    __shared__ unsigned short Ah[128][40];
    __shared__ unsigned short Al[128][40];
    __shared__ unsigned short Bh[128][40];
    __shared__ unsigned short Bl[128][40];
    f32x4 acc[4][4];
    #pragma unroll
    for (int i=0;i<4;i++)
        #pragma unroll
        for (int j=0;j<4;j++) acc[i][j] = (f32x4){0.f,0.f,0.f,0.f};

    const size_t srcB = (size_t)b*N_*C_;
    for (int ks=0; ks<16; ks++){
        const int c0 = ks*32;
        #pragma unroll
        for (int i=0;i<2;i++){
            int u = t + i*256;
            int row = u>>2, sch = (u&3)*8;
            *(bf16x8*)&Ah[row][sch] = *(const bf16x8*)(Wh + (size_t)(o0+row)*C_ + c0 + sch);
            *(bf16x8*)&Bh[row][sch] = *(const bf16x8*)(Sh + srcB + (size_t)(n0+row)*C_ + c0 + sch);
            if constexpr (PROD==3){
                *(bf16x8*)&Al[row][sch] = *(const bf16x8*)(Wl + (size_t)(o0+row)*C_ + c0 + sch);
                *(bf16x8*)&Bl[row][sch] = *(const bf16x8*)(Sl + srcB + (size_t)(n0+row)*C_ + c0 + sch);
            }
        }
        __syncthreads();
        bf16x8 af[4], bfv[4], afl[4], bfl[4];
        #pragma unroll
        for (int i=0;i<4;i++){
            af[i]  = *(const bf16x8*)&Ah[ro + i*16 + lr][lg*8];
            bfv[i] = *(const bf16x8*)&Bh[co + i*16 + lr][lg*8];
            if constexpr (PROD==3){
                afl[i] = *(const bf16x8*)&Al[ro + i*16 + lr][lg*8];
                bfl[i] = *(const bf16x8*)&Bl[co + i*16 + lr][lg*8];
            }
        }
        #pragma unroll
        for (int i=0;i<4;i++)
            #pragma unroll
            for (int j=0;j<4;j++){
                acc[i][j] = mfma16(af[i], bfv[j], acc[i][j]);
                if constexpr (PROD==3){
                    acc[i][j] = mfma16(af[i],  bfl[j], acc[i][j]);
                    acc[i][j] = mfma16(afl[i], bfv[j], acc[i][j]);
                }
            }
        __syncthreads();
    }
    #pragma unroll
    for (int i=0;i<4;i++){
        const int ob = o0 + ro + i*16 + lg*4;
        #pragma unroll
        for (int j=0;j<4;j++){
            const int n = n0 + co + j*16 + lr;
            f32x4 v = acc[i][j];
            if constexpr (MODE==0){
                float v0 = v[0] + bias[ob+0]; unsigned short h0 = f2bf(v0);
                float v1 = v[1] + bias[ob+1]; unsigned short h1 = f2bf(v1);
                float v2 = v[2] + bias[ob+2]; unsigned short h2 = f2bf(v2);
                float v3 = v[3] + bias[ob+3]; unsigned short h3 = f2bf(v3);
                ushort4 hh, ll;
                hh.x=h0; hh.y=h1; hh.z=h2; hh.w=h3;
                ll.x=f2bf(v0-bf2f(h0)); ll.y=f2bf(v1-bf2f(h1));
                ll.z=f2bf(v2-bf2f(h2)); ll.w=f2bf(v3-bf2f(h3));
                *(ushort4*)(outHi + srcB + (size_t)n*C_ + ob) = hh;
                *(ushort4*)(outLo + srcB + (size_t)n*C_ + ob) = ll;
            } else if constexpr (MODE==1){
                #pragma unroll
                for (int r=0;r<4;r++)
                    outHi[((size_t)b*C_ + ob + r)*N_ + n] = f2bf(v[r] + bias[ob+r]);
            } else {
                #pragma unroll
                for (int r=0;r<4;r++){
                    size_t idx = ((size_t)b*C_ + ob + r)*N_ + n;
                    outF[idx] = resid[idx] + v[r] + bias[ob+r];
                }
            }
        }
    }
}

// ---------------- flash attention v3: 64 q-rows/block, 256 blocks ----------------
// 8 waves: QK roles (fm2 x fn x ch): 2 q-row-frags x 16 m-cols x c-half each,
// partial S summed via Sb[2]. PV roles: wave w owns c-cols w*64..+64.
// K double-buffered via global_load_lds (pre-swizzled source), counted waits:
// DMA stays in flight across softmax+PV; drained only at post-PV vmcnt(0).
__global__ __launch_bounds__(512, 2) void attn_flash3(
    const unsigned short* __restrict__ qTh, const unsigned short* __restrict__ qTl,
    const unsigned short* __restrict__ kTh, const unsigned short* __restrict__ kTl,
    const unsigned short* __restrict__ vB,  unsigned short* __restrict__ aoT)
{
    const int b = blockIdx.y, n0 = blockIdx.x*64;
    const int t = threadIdx.x, w = t>>6, l = t&63, lr = l&15, lg = l>>4;
    const int fm2 = w>>2, fn = (w>>1)&1, ch = w&1;
    const int cw = w*64;

    __shared__ unsigned short khA[32*512];
    __shared__ unsigned short klA[32*512];
    __shared__ unsigned short khB[32*512];
    __shared__ unsigned short klB[32*512];
    __shared__ float Sb[2][64][34];
    __shared__ __align__(16) unsigned short Pb[64][40];
    __shared__ float rowM[64], rowS[64], rowF[64];

    // q fragments: 2 row-frags (fm2*32 + f*16), c-half ch, hi+lo -> 128 VGPR
    bf16x8 qh[2][8], ql[2][8];
    #pragma unroll
    for (int f=0; f<2; f++){
        const size_t qr = ((size_t)b*N_ + n0 + fm2*32 + f*16 + lr)*C_ + ch*256;
        #pragma unroll
        for (int kc=0; kc<8; kc++){
            qh[f][kc] = *(const bf16x8*)(qTh + qr + kc*32 + lg*8);
            ql[f][kc] = *(const bf16x8*)(qTl + qr + kc*32 + lg*8);
        }
    }
    f32x4 accO[4][4];
    #pragma unroll
    for (int i=0;i<4;i++)
        #pragma unroll
        for (int j=0;j<4;j++) accO[i][j] = (f32x4){0.f,0.f,0.f,0.f};
    if (t < 64){ rowM[t] = -INFINITY; rowS[t] = 0.f; rowF[t] = 1.f; }

    const size_t kBase = (size_t)b*N_*1024;   // bytes; C_*2 per row

    auto stage = [&](int mt, unsigned short* dh, unsigned short* dl){
        const size_t kb = kBase + (size_t)mt*32*1024;
        #pragma unroll
        for (int i=0;i<4;i++){
            const int d = i*8192 + t*16;
            const int row = i*8 + w;
            const int colb = (l*16) ^ ((row&7)<<4);
            const size_t g = kb + (size_t)row*1024 + colb;
            __builtin_amdgcn_global_load_lds(AS1((const char*)kTh + g), AS3((char*)dh + d), 16, 0, 0);
            __builtin_amdgcn_global_load_lds(AS1((const char*)kTl + g), AS3((char*)dl + d), 16, 0, 0);
        }
    };

    stage(0, khA, klA);
    bar_vm();

    for (int mt=0; mt<128; mt++){
        const int cur = mt & 1;
        const unsigned short* kh = cur ? khB : khA;
        const unsigned short* kl = cur ? klB : klA;

        // ---- V prefetch for this mt (consumed in PV) ----
        bf16x8 vf[4];
        {
            const size_t vcol = (size_t)mt*32 + lg*8;
            #pragma unroll
            for (int ac=0;ac<4;ac++)
                vf[ac] = *(const bf16x8*)(vB + ((size_t)b*C_ + cw + ac*16 + lr)*N_ + vcol);
        }

        // ---- QK^T partial: rows fm2 (2 frags), cols fn, c-half ch ----
        f32x4 s0 = (f32x4){0.f,0.f,0.f,0.f}, s1 = s0;
        {
            const int krow = fn*16 + lr;
            const int rbase = krow*1024;
            const int swz = (krow&7)<<4;
            #pragma unroll
            for (int kc=0;kc<8;kc++){
                const int o = rbase + ((ch*512 + kc*64 + lg*16) ^ swz);
                bf16x8 kf  = *(const bf16x8*)((const char*)kh + o);
                bf16x8 kfl = *(const bf16x8*)((const char*)kl + o);
                s0 = mfma16(qh[0][kc], kf,  s0);
                s0 = mfma16(ql[0][kc], kf,  s0);
                s0 = mfma16(qh[0][kc], kfl, s0);
                s1 = mfma16(qh[1][kc], kf,  s1);
                s1 = mfma16(ql[1][kc], kf,  s1);
                s1 = mfma16(qh[1][kc], kfl, s1);
            }
        }
        #pragma unroll
        for (int r=0;r<4;r++){
            Sb[ch][fm2*32 +      lg*4 + r][fn*16 + lr] = s0[r];
            Sb[ch][fm2*32 + 16 + lg*4 + r][fn*16 + lr] = s1[r];
        }
        // issue async K stage for next tile BEFORE the barrier; stays in
        // flight through softmax + PV (drained at bar_vm below)
        if (mt < 127) stage(mt+1, cur ? khA : khB, cur ? klA : klB);
        bar_lgkm();

        // ---- online softmax: 8 threads/row, 4 cols each ----
        {
            const int row = t>>3, j = t&7;
            const float* p0v = &Sb[0][row][j*4];
            const float* p1v = &Sb[1][row][j*4];
            float2 u0 = *(const float2*)p0v, u1 = *(const float2*)(p0v+2);
            float2 w0 = *(const float2*)p1v, w1 = *(const float2*)(p1v+2);
            const float SC = 22.62741699796952f;
            float a0 = (u0.x + w0.x)*SC, a1 = (u0.y + w0.y)*SC;
            float a2 = (u1.x + w1.x)*SC, a3 = (u1.y + w1.y)*SC;
            float mx = fmaxf(fmaxf(a0,a1), fmaxf(a2,a3));
            mx = fmaxf(mx, __shfl_xor(mx, 1, 8));
            mx = fmaxf(mx, __shfl_xor(mx, 2, 8));
            mx = fmaxf(mx, __shfl_xor(mx, 4, 8));
            const float mprev = rowM[row];
            const float mnew = fmaxf(mprev, mx);
            float p0 = __expf(a0 - mnew), p1 = __expf(a1 - mnew);
            float p2 = __expf(a2 - mnew), p3 = __expf(a3 - mnew);
            float ps = (p0+p1)+(p2+p3);
            ps += __shfl_xor(ps, 1, 8);
            ps += __shfl_xor(ps, 2, 8);
            ps += __shfl_xor(ps, 4, 8);
            ushort4 pk; pk.x=f2bf(p0); pk.y=f2bf(p1); pk.z=f2bf(p2); pk.w=f2bf(p3);
            *(ushort4*)&Pb[row][j*4] = pk;
            if (j==0){
                float f = __expf(mprev - mnew);
                rowF[row] = f;
                rowS[row] = rowS[row]*f + ps;
                rowM[row] = mnew;
            }
        }
        bar_lgkm();

        // ---- rescale (gated) + PV ----
        {
            float frv[4][4]; bool need = false;
            #pragma unroll
            for (int am=0;am<4;am++)
                #pragma unroll
                for (int r=0;r<4;r++){
                    frv[am][r] = rowF[am*16 + lg*4 + r];
                    need |= (frv[am][r] != 1.0f);
                }
            if (__any(need)){
                #pragma unroll
                for (int am=0;am<4;am++)
                    #pragma unroll
                    for (int ac=0;ac<4;ac++)
                        #pragma unroll
                        for (int r=0;r<4;r++) accO[am][ac][r] *= frv[am][r];
            }
            bf16x8 pa[4];
            #pragma unroll
            for (int am=0;am<4;am++) pa[am] = *(const bf16x8*)&Pb[am*16 + lr][lg*8];
            #pragma unroll
            for (int ac=0;ac<4;ac++)
                #pragma unroll
                for (int am=0;am<4;am++)
                    accO[am][ac] = mfma16(pa[am], vf[ac], accO[am][ac]);
        }
        // drain K DMA (+ consumed V loads), then allow next tile's reads
        bar_vm();
    }

    // ---- normalize + write aoT[B][N][C] ----
    #pragma unroll
    for (int am=0;am<4;am++)
        #pragma unroll
        for (int r=0;r<4;r++){
            const int n = am*16 + lg*4 + r;
            const float inv = 1.0f / rowS[n];
            #pragma unroll
            for (int ac=0;ac<4;ac++)
                aoT[((size_t)b*N_ + n0 + n)*C_ + cw + ac*16 + lr] = f2bf(accO[am][ac][r]*inv);
        }
}

extern "C" void kernel_launch(void* const* d_in, const int* in_sizes, int n_in,
                              void* d_out, int out_size, void* d_ws, size_t ws_size,
                              hipStream_t stream)
{
    const float* x   = (const float*)d_in[0];
    const float* gnw = (const float*)d_in[1];
    const float* gnb = (const float*)d_in[2];
    const float* wq  = (const float*)d_in[3];
    const float* bq  = (const float*)d_in[4];
    const float* wk  = (const float*)d_in[5];
    const float* bk  = (const float*)d_in[6];
    const float* wv  = (const float*)d_in[7];
    const float* bv  = (const float*)d_in[8];
    const float* wp  = (const float*)d_in[9];
    const float* bp  = (const float*)d_in[10];
    float* out = (float*)d_out;

    char* ws = (char*)d_ws;
    size_t off = 0;
    auto alloc = [&](size_t bytes)->char*{
        char* p = ws + off; off += (bytes + 255) & ~(size_t)255; return p;
    };
    const size_t WB = (size_t)C_*C_*2;
    const size_t TB = (size_t)B_*N_*C_*2;
    unsigned short* wqh = (unsigned short*)alloc(WB);
    unsigned short* wql = (unsigned short*)alloc(WB);
    unsigned short* wkh = (unsigned short*)alloc(WB);
    unsigned short* wkl = (unsigned short*)alloc(WB);
    unsigned short* wvh = (unsigned short*)alloc(WB);
    unsigned short* wvl = (unsigned short*)alloc(WB);
    unsigned short* wph = (unsigned short*)alloc(WB);
    unsigned short* wpl = (unsigned short*)alloc(WB);
    unsigned short* hTh = (unsigned short*)alloc(TB);
    unsigned short* hTl = (unsigned short*)alloc(TB);
    unsigned short* qTh = (unsigned short*)alloc(TB);
    unsigned short* qTl = (unsigned short*)alloc(TB);
    unsigned short* kTh = (unsigned short*)alloc(TB);
    unsigned short* kTl = (unsigned short*)alloc(TB);
    unsigned short* vb  = (unsigned short*)alloc(TB);
    unsigned short* ao  = (unsigned short*)alloc(TB);
    float2* part  = (float2*)alloc(8*64*sizeof(float2));
    float2* stats = (float2*)alloc(8*sizeof(float2));

    split_w<<<256, 256, 0, stream>>>(wq, wqh, wql);
    split_w<<<256, 256, 0, stream>>>(wk, wkh, wkl);
    split_w<<<256, 256, 0, stream>>>(wv, wvh, wvl);
    split_w<<<256, 256, 0, stream>>>(wp, wph, wpl);
    gn_part<<<dim3(64, 8), 256, 0, stream>>>(x, part);
    gn_fin<<<8, 64, 0, stream>>>(part, stats);
    gn_apply<<<dim3(128, 16, B_), 256, 0, stream>>>(x, gnw, gnb, stats, hTh, hTl);
    conv_gemm<3,0><<<dim3(32,4,B_), 256, 0, stream>>>(wqh,wql,hTh,hTl,bq, qTh,qTl,nullptr,nullptr);
    conv_gemm<3,0><<<dim3(32,4,B_), 256, 0, stream>>>(wkh,wkl,hTh,hTl,bk, kTh,kTl,nullptr,nullptr);
    conv_gemm<1,1><<<dim3(32,4,B_), 256, 0, stream>>>(wvh,wvl,hTh,hTl,bv, vb,nullptr,nullptr,nullptr);
    attn_flash3<<<dim3(64, B_), 512, 0, stream>>>(qTh,qTl,kTh,kTl,vb,ao);
    conv_gemm<1,2><<<dim3(32,4,B_), 256, 0, stream>>>(wph,wpl,ao,nullptr,bp, nullptr,nullptr,out,x);
}

// Round 4
// 494.924 us; speedup vs baseline: 2.8841x; 1.0958x over previous
//
#include <hip/hip_runtime.h>
#include <hip/hip_bf16.h>
#include <math.h>

#define B_ 4
#define C_ 512
#define N_ 4096

typedef float f32x4 __attribute__((ext_vector_type(4)));
typedef __bf16 bf16x8 __attribute__((ext_vector_type(8)));

#define AS1(p) ((const __attribute__((address_space(1))) unsigned int*)(p))
#define AS3(p) ((__attribute__((address_space(3))) unsigned int*)(p))

__device__ __forceinline__ unsigned short f2bf(float x){
    return __builtin_bit_cast(unsigned short, (__bf16)x);
}
__device__ __forceinline__ float bf2f(unsigned short b){
    unsigned u = ((unsigned)b)<<16;
    return __builtin_bit_cast(float, u);
}
__device__ __forceinline__ f32x4 mfma16(bf16x8 a, bf16x8 b, f32x4 c){
    return __builtin_amdgcn_mfma_f32_16x16x32_bf16(a, b, c, 0, 0, 0);
}

// ---------------- weight fp32 -> bf16 hi/lo split ----------------
__global__ void split_w(const float* __restrict__ src, unsigned short* __restrict__ hi,
                        unsigned short* __restrict__ lo){
    const int i = (blockIdx.x*256 + threadIdx.x)*4;
    f32x4 v = *(const f32x4*)(src + i);
    ushort4 h, l;
    unsigned short t0=f2bf(v[0]); h.x=t0; l.x=f2bf(v[0]-bf2f(t0));
    unsigned short t1=f2bf(v[1]); h.y=t1; l.y=f2bf(v[1]-bf2f(t1));
    unsigned short t2=f2bf(v[2]); h.z=t2; l.z=f2bf(v[2]-bf2f(t2));
    unsigned short t3=f2bf(v[3]); h.w=t3; l.w=f2bf(v[3]-bf2f(t3));
    *(ushort4*)(hi + i) = h;
    *(ushort4*)(lo + i) = l;
}

// ---------------- GroupNorm: partial sums ----------------
__global__ void gn_part(const float* __restrict__ x, float2* __restrict__ part){
    const int bg = blockIdx.y, blk = blockIdx.x, t = threadIdx.x;
    const float* base = x + (size_t)bg*(256*4096) + (size_t)blk*16384;
    float s = 0.f, q = 0.f;
    for (int i=0;i<16;i++){
        f32x4 v = *(const f32x4*)(base + i*1024 + t*4);
        s += v[0]+v[1]+v[2]+v[3];
        q += v[0]*v[0]+v[1]*v[1]+v[2]*v[2]+v[3]*v[3];
    }
    #pragma unroll
    for (int o=32;o>0;o>>=1){ s += __shfl_down(s, o); q += __shfl_down(q, o); }
    __shared__ float as[4], aq[4];
    if ((t&63)==0){ as[t>>6]=s; aq[t>>6]=q; }
    __syncthreads();
    if (t==0)
        part[bg*64 + blk] = make_float2(as[0]+as[1]+as[2]+as[3], aq[0]+aq[1]+aq[2]+aq[3]);
}

__global__ void gn_fin(const float2* __restrict__ part, float2* __restrict__ stats){
    const int bg = blockIdx.x, t = threadIdx.x;
    float2 p = part[bg*64 + t];
    float s = p.x, q = p.y;
    #pragma unroll
    for (int o=32;o>0;o>>=1){ s += __shfl_down(s,o); q += __shfl_down(q,o); }
    if (t==0){
        const float inv = 1.0f/(256.f*4096.f);
        float mu = s*inv;
        float var = q*inv - mu*mu;
        stats[bg] = make_float2(mu, rsqrtf(var + 1e-6f));
    }
}

// ---- GN apply + transpose + hi/lo split: x[B][C][N] -> hT[B][N][C] (bf16 hi,lo) ----
__global__ void gn_apply(const float* __restrict__ x, const float* __restrict__ gw,
                         const float* __restrict__ gb, const float2* __restrict__ stats,
                         unsigned short* __restrict__ hTh, unsigned short* __restrict__ hTl)
{
    const int b = blockIdx.z, c0 = blockIdx.y*32, n0 = blockIdx.x*32;
    const int t = threadIdx.x;
    __shared__ float tile[32][37];
    {
        const int cl = t>>3, nl = (t&7)*4;
        const int c = c0 + cl;
        const float2 st = stats[b*2 + (c>>8)];
        const float wv = gw[c], bvv = gb[c];
        const f32x4 v = *(const f32x4*)(x + ((size_t)b*C_ + c)*N_ + n0 + nl);
        #pragma unroll
        for (int i=0;i<4;i++) tile[cl][nl+i] = (v[i] - st.x)*st.y*wv + bvv;
    }
    __syncthreads();
    {
        const int nl = t>>3, cl = (t&7)*4;
        const int n = n0 + nl;
        float f0 = tile[cl+0][nl], f1 = tile[cl+1][nl], f2 = tile[cl+2][nl], f3 = tile[cl+3][nl];
        unsigned short h0=f2bf(f0), h1=f2bf(f1), h2=f2bf(f2), h3=f2bf(f3);
        ushort4 hh, ll;
        hh.x=h0; hh.y=h1; hh.z=h2; hh.w=h3;
        ll.x=f2bf(f0-bf2f(h0)); ll.y=f2bf(f1-bf2f(h1));
        ll.z=f2bf(f2-bf2f(h2)); ll.w=f2bf(f3-bf2f(h3));
        size_t o = ((size_t)b*N_ + n)*C_ + c0 + cl;
        *(ushort4*)(hTh + o) = hh;
        *(ushort4*)(hTl + o) = ll;
    }
}

// ---------------- conv GEMM: out[o,n] = sum_c W[o,c]*S[c,n] + bias[o] ----------------
template<int PROD, int MODE>
__global__ __launch_bounds__(256, 2) void conv_gemm(
    const unsigned short* __restrict__ Wh, const unsigned short* __restrict__ Wl,
    const unsigned short* __restrict__ Sh, const unsigned short* __restrict__ Sl,
    const float* __restrict__ bias,
    unsigned short* __restrict__ outHi, unsigned short* __restrict__ outLo,
    float* __restrict__ outF, const float* __restrict__ resid)
{
    const int b = blockIdx.z, o0 = blockIdx.y*128, n0 = blockIdx.x*128;
    const int t = threadIdx.x, w = t>>6, l = t&63, lr = l&15, lg = l>>4;
    const int ro = (w>>1)*64, co = (w&1)*64;
    __shared__ unsigned short Ah[128][40];
    __shared__ unsigned short Al[128][40];
    __shared__ unsigned short Bh[128][40];
    __shared__ unsigned short Bl[128][40];
    f32x4 acc[4][4];
    #pragma unroll
    for (int i=0;i<4;i++)
        #pragma unroll
        for (int j=0;j<4;j++) acc[i][j] = (f32x4){0.f,0.f,0.f,0.f};

    const size_t srcB = (size_t)b*N_*C_;
    for (int ks=0; ks<16; ks++){
        const int c0 = ks*32;
        #pragma unroll
        for (int i=0;i<2;i++){
            int u = t + i*256;
            int row = u>>2, sch = (u&3)*8;
            *(bf16x8*)&Ah[row][sch] = *(const bf16x8*)(Wh + (size_t)(o0+row)*C_ + c0 + sch);
            *(bf16x8*)&Bh[row][sch] = *(const bf16x8*)(Sh + srcB + (size_t)(n0+row)*C_ + c0 + sch);
            if constexpr (PROD==3){
                *(bf16x8*)&Al[row][sch] = *(const bf16x8*)(Wl + (size_t)(o0+row)*C_ + c0 + sch);
                *(bf16x8*)&Bl[row][sch] = *(const bf16x8*)(Sl + srcB + (size_t)(n0+row)*C_ + c0 + sch);
            }
        }
        __syncthreads();
        bf16x8 af[4], bfv[4], afl[4], bfl[4];
        #pragma unroll
        for (int i=0;i<4;i++){
            af[i]  = *(const bf16x8*)&Ah[ro + i*16 + lr][lg*8];
            bfv[i] = *(const bf16x8*)&Bh[co + i*16 + lr][lg*8];
            if constexpr (PROD==3){
                afl[i] = *(const bf16x8*)&Al[ro + i*16 + lr][lg*8];
                bfl[i] = *(const bf16x8*)&Bl[co + i*16 + lr][lg*8];
            }
        }
        #pragma unroll
        for (int i=0;i<4;i++)
            #pragma unroll
            for (int j=0;j<4;j++){
                acc[i][j] = mfma16(af[i], bfv[j], acc[i][j]);
                if constexpr (PROD==3){
                    acc[i][j] = mfma16(af[i],  bfl[j], acc[i][j]);
                    acc[i][j] = mfma16(afl[i], bfv[j], acc[i][j]);
                }
            }
        __syncthreads();
    }
    #pragma unroll
    for (int i=0;i<4;i++){
        const int ob = o0 + ro + i*16 + lg*4;
        #pragma unroll
        for (int j=0;j<4;j++){
            const int n = n0 + co + j*16 + lr;
            f32x4 v = acc[i][j];
            if constexpr (MODE==0){
                float v0 = v[0] + bias[ob+0]; unsigned short h0 = f2bf(v0);
                float v1 = v[1] + bias[ob+1]; unsigned short h1 = f2bf(v1);
                float v2 = v[2] + bias[ob+2]; unsigned short h2 = f2bf(v2);
                float v3 = v[3] + bias[ob+3]; unsigned short h3 = f2bf(v3);
                ushort4 hh, ll;
                hh.x=h0; hh.y=h1; hh.z=h2; hh.w=h3;
                ll.x=f2bf(v0-bf2f(h0)); ll.y=f2bf(v1-bf2f(h1));
                ll.z=f2bf(v2-bf2f(h2)); ll.w=f2bf(v3-bf2f(h3));
                *(ushort4*)(outHi + srcB + (size_t)n*C_ + ob) = hh;
                *(ushort4*)(outLo + srcB + (size_t)n*C_ + ob) = ll;
            } else if constexpr (MODE==1){
                #pragma unroll
                for (int r=0;r<4;r++)
                    outHi[((size_t)b*C_ + ob + r)*N_ + n] = f2bf(v[r] + bias[ob+r]);
            } else {
                #pragma unroll
                for (int r=0;r<4;r++){
                    size_t idx = ((size_t)b*C_ + ob + r)*N_ + n;
                    outF[idx] = resid[idx] + v[r] + bias[ob+r];
                }
            }
        }
    }
}

// ---------------- flash attention v4: two-phase pipelined loop ----------------
// grid 256 1-D, XCD-aware: 2 XCDs per batch so K/V tiles are L2-shared.
// Per mt: [softmax(t)] barv [stage K(t+2) | PV(t) | V(t+1) | QK(t+1)] barl.
// K DMA + V register loads stay in flight across both barriers + softmax.
__global__ __launch_bounds__(512, 2) void attn_flash4(
    const unsigned short* __restrict__ qTh, const unsigned short* __restrict__ qTl,
    const unsigned short* __restrict__ kTh, const unsigned short* __restrict__ kTl,
    const unsigned short* __restrict__ vB,  unsigned short* __restrict__ aoT)
{
    const int id = blockIdx.x;
    const int xcd = id & 7, slot = id >> 3;
    const int b = xcd >> 1;
    const int n0 = ((xcd & 1)*32 + slot)*64;
    const int t = threadIdx.x, w = t>>6, l = t&63, lr = l&15, lg = l>>4;
    const int fm2 = w>>2, fn = (w>>1)&1, ch = w&1;
    const int cw = w*64;

    __shared__ unsigned short khA[32*512];
    __shared__ unsigned short klA[32*512];
    __shared__ unsigned short khB[32*512];
    __shared__ unsigned short klB[32*512];
    __shared__ float Sb[2][64][33];
    __shared__ __align__(16) unsigned short Pb[64*32];  // swizzled [row][32]
    __shared__ float rowM[64], rowS[64], rowF[64];

    // q fragments: 2 row-frags (fm2*32 + f*16), c-half ch, hi+lo
    bf16x8 qh[2][8], ql[2][8];
    #pragma unroll
    for (int f=0; f<2; f++){
        const size_t qr = ((size_t)b*N_ + n0 + fm2*32 + f*16 + lr)*C_ + ch*256;
        #pragma unroll
        for (int kc=0; kc<8; kc++){
            qh[f][kc] = *(const bf16x8*)(qTh + qr + kc*32 + lg*8);
            ql[f][kc] = *(const bf16x8*)(qTl + qr + kc*32 + lg*8);
        }
    }
    f32x4 accO[4][4];
    #pragma unroll
    for (int i=0;i<4;i++)
        #pragma unroll
        for (int j=0;j<4;j++) accO[i][j] = (f32x4){0.f,0.f,0.f,0.f};
    if (t < 64){ rowM[t] = -INFINITY; rowS[t] = 0.f; }

    const size_t kBase = (size_t)b*N_*1024;   // bytes; C_*2 per row

    auto stage = [&](int mt, unsigned short* dh, unsigned short* dl){
        const size_t kb = kBase + (size_t)mt*32*1024;
        #pragma unroll
        for (int i=0;i<4;i++){
            const int d = i*8192 + t*16;
            const int row = i*8 + w;
            const int colb = (l*16) ^ ((row&7)<<4);
            const size_t g = kb + (size_t)row*1024 + colb;
            __builtin_amdgcn_global_load_lds(AS1((const char*)kTh + g), AS3((char*)dh + d), 16, 0, 0);
            __builtin_amdgcn_global_load_lds(AS1((const char*)kTl + g), AS3((char*)dl + d), 16, 0, 0);
        }
    };
    auto loadV = [&](int mt, bf16x8* vf){
        const size_t vcol = (size_t)mt*32 + lg*8;
        #pragma unroll
        for (int ac=0;ac<4;ac++)
            vf[ac] = *(const bf16x8*)(vB + ((size_t)b*C_ + cw + ac*16 + lr)*N_ + vcol);
    };
    const float SC = 22.62741699796952f;
    auto qk_tile = [&](const unsigned short* kh, const unsigned short* kl){
        f32x4 s0 = (f32x4){0.f,0.f,0.f,0.f}, s1 = s0;
        const int krow = fn*16 + lr;
        const int rbase = krow*1024;
        const int swz = (krow&7)<<4;
        #pragma unroll
        for (int kc=0;kc<8;kc++){
            const int o = rbase + ((ch*512 + kc*64 + lg*16) ^ swz);
            bf16x8 kf  = *(const bf16x8*)((const char*)kh + o);
            bf16x8 kfl = *(const bf16x8*)((const char*)kl + o);
            s0 = mfma16(qh[0][kc], kf,  s0);
            s0 = mfma16(ql[0][kc], kf,  s0);
            s0 = mfma16(qh[0][kc], kfl, s0);
            s1 = mfma16(qh[1][kc], kf,  s1);
            s1 = mfma16(ql[1][kc], kf,  s1);
            s1 = mfma16(qh[1][kc], kfl, s1);
        }
        #pragma unroll
        for (int r=0;r<4;r++){
            Sb[ch][fm2*32 +      lg*4 + r][fn*16 + lr] = s0[r]*SC;
            Sb[ch][fm2*32 + 16 + lg*4 + r][fn*16 + lr] = s1[r]*SC;
        }
    };

    bf16x8 vf[4];
    loadV(0, vf);
    stage(0, khA, klA);
    asm volatile("s_waitcnt vmcnt(0) lgkmcnt(0)" ::: "memory");
    __builtin_amdgcn_s_barrier();
    // phase2(-1): prefetch tile1 + compute S(0)
    stage(1, khB, klB);
    qk_tile(khA, klA);
    asm volatile("s_waitcnt lgkmcnt(0)" ::: "memory");
    __builtin_amdgcn_s_barrier();

    for (int mt=0; mt<128; mt++){
        // ---- phase1: online softmax for tile mt ----
        {
            const int row = t>>3, j = t&7;
            const float* s0p = &Sb[0][row][j*4];
            const float* s1p = &Sb[1][row][j*4];
            float a0 = s0p[0] + s1p[0];
            float a1 = s0p[1] + s1p[1];
            float a2 = s0p[2] + s1p[2];
            float a3 = s0p[3] + s1p[3];
            float mx = fmaxf(fmaxf(a0,a1), fmaxf(a2,a3));
            mx = fmaxf(mx, __shfl_xor(mx, 1, 8));
            mx = fmaxf(mx, __shfl_xor(mx, 2, 8));
            mx = fmaxf(mx, __shfl_xor(mx, 4, 8));
            const float mprev = rowM[row];
            const float mnew = fmaxf(mprev, mx);
            float p0 = __expf(a0 - mnew), p1 = __expf(a1 - mnew);
            float p2 = __expf(a2 - mnew), p3 = __expf(a3 - mnew);
            float ps = (p0+p1)+(p2+p3);
            ps += __shfl_xor(ps, 1, 8);
            ps += __shfl_xor(ps, 2, 8);
            ps += __shfl_xor(ps, 4, 8);
            ushort4 pk; pk.x=f2bf(p0); pk.y=f2bf(p1); pk.z=f2bf(p2); pk.w=f2bf(p3);
            char* pw = (char*)Pb + row*64 + ((((j>>1) + (row>>1)) & 3)<<4) + ((j&1)<<3);
            *(ushort4*)pw = pk;
            if (j==0){
                float f = __expf(mprev - mnew);
                rowF[row] = f;
                rowS[row] = rowS[row]*f + ps;
                rowM[row] = mnew;
            }
        }
        asm volatile("s_waitcnt vmcnt(0) lgkmcnt(0)" ::: "memory");
        __builtin_amdgcn_s_barrier();

        // ---- phase2: stage(t+2) | PV(t) | V(t+1) | QK(t+1) ----
        if (mt < 126) stage(mt+2, (mt&1) ? khB : khA, (mt&1) ? klB : klA);
        __builtin_amdgcn_s_setprio(1);
        {
            float frv[4][4]; bool need = false;
            #pragma unroll
            for (int am=0;am<4;am++)
                #pragma unroll
                for (int r=0;r<4;r++){
                    frv[am][r] = rowF[am*16 + lg*4 + r];
                    need |= (frv[am][r] != 1.0f);
                }
            if (__any(need)){
                #pragma unroll
                for (int am=0;am<4;am++)
                    #pragma unroll
                    for (int ac=0;ac<4;ac++)
                        #pragma unroll
                        for (int r=0;r<4;r++) accO[am][ac][r] *= frv[am][r];
            }
            bf16x8 pa[4];
            #pragma unroll
            for (int am=0;am<4;am++){
                const int prow = am*16 + lr;
                pa[am] = *(const bf16x8*)((const char*)Pb + prow*64 + (((lg + (prow>>1)) & 3)<<4));
            }
            #pragma unroll
            for (int ac=0;ac<4;ac++)
                #pragma unroll
                for (int am=0;am<4;am++)
                    accO[am][ac] = mfma16(pa[am], vf[ac], accO[am][ac]);
        }
        if (mt < 127){
            loadV(mt+1, vf);
            qk_tile(((mt+1)&1) ? khB : khA, ((mt+1)&1) ? klB : klA);
        }
        __builtin_amdgcn_s_setprio(0);
        asm volatile("s_waitcnt lgkmcnt(0)" ::: "memory");
        __builtin_amdgcn_s_barrier();
    }

    // ---- normalize + write aoT[B][N][C] ----
    #pragma unroll
    for (int am=0;am<4;am++)
        #pragma unroll
        for (int r=0;r<4;r++){
            const int n = am*16 + lg*4 + r;
            const float inv = 1.0f / rowS[n];
            #pragma unroll
            for (int ac=0;ac<4;ac++)
                aoT[((size_t)b*N_ + n0 + n)*C_ + cw + ac*16 + lr] = f2bf(accO[am][ac][r]*inv);
        }
}

extern "C" void kernel_launch(void* const* d_in, const int* in_sizes, int n_in,
                              void* d_out, int out_size, void* d_ws, size_t ws_size,
                              hipStream_t stream)
{
    const float* x   = (const float*)d_in[0];
    const float* gnw = (const float*)d_in[1];
    const float* gnb = (const float*)d_in[2];
    const float* wq  = (const float*)d_in[3];
    const float* bq  = (const float*)d_in[4];
    const float* wk  = (const float*)d_in[5];
    const float* bk  = (const float*)d_in[6];
    const float* wv  = (const float*)d_in[7];
    const float* bv  = (const float*)d_in[8];
    const float* wp  = (const float*)d_in[9];
    const float* bp  = (const float*)d_in[10];
    float* out = (float*)d_out;

    char* ws = (char*)d_ws;
    size_t off = 0;
    auto alloc = [&](size_t bytes)->char*{
        char* p = ws + off; off += (bytes + 255) & ~(size_t)255; return p;
    };
    const size_t WB = (size_t)C_*C_*2;
    const size_t TB = (size_t)B_*N_*C_*2;
    unsigned short* wqh = (unsigned short*)alloc(WB);
    unsigned short* wql = (unsigned short*)alloc(WB);
    unsigned short* wkh = (unsigned short*)alloc(WB);
    unsigned short* wkl = (unsigned short*)alloc(WB);
    unsigned short* wvh = (unsigned short*)alloc(WB);
    unsigned short* wvl = (unsigned short*)alloc(WB);
    unsigned short* wph = (unsigned short*)alloc(WB);
    unsigned short* wpl = (unsigned short*)alloc(WB);
    unsigned short* hTh = (unsigned short*)alloc(TB);
    unsigned short* hTl = (unsigned short*)alloc(TB);
    unsigned short* qTh = (unsigned short*)alloc(TB);
    unsigned short* qTl = (unsigned short*)alloc(TB);
    unsigned short* kTh = (unsigned short*)alloc(TB);
    unsigned short* kTl = (unsigned short*)alloc(TB);
    unsigned short* vb  = (unsigned short*)alloc(TB);
    unsigned short* ao  = (unsigned short*)alloc(TB);
    float2* part  = (float2*)alloc(8*64*sizeof(float2));
    float2* stats = (float2*)alloc(8*sizeof(float2));

    split_w<<<256, 256, 0, stream>>>(wq, wqh, wql);
    split_w<<<256, 256, 0, stream>>>(wk, wkh, wkl);
    split_w<<<256, 256, 0, stream>>>(wv, wvh, wvl);
    split_w<<<256, 256, 0, stream>>>(wp, wph, wpl);
    gn_part<<<dim3(64, 8), 256, 0, stream>>>(x, part);
    gn_fin<<<8, 64, 0, stream>>>(part, stats);
    gn_apply<<<dim3(128, 16, B_), 256, 0, stream>>>(x, gnw, gnb, stats, hTh, hTl);
    conv_gemm<3,0><<<dim3(32,4,B_), 256, 0, stream>>>(wqh,wql,hTh,hTl,bq, qTh,qTl,nullptr,nullptr);
    conv_gemm<3,0><<<dim3(32,4,B_), 256, 0, stream>>>(wkh,wkl,hTh,hTl,bk, kTh,kTl,nullptr,nullptr);
    conv_gemm<1,1><<<dim3(32,4,B_), 256, 0, stream>>>(wvh,wvl,hTh,hTl,bv, vb,nullptr,nullptr,nullptr);
    attn_flash4<<<dim3(256), 512, 0, stream>>>(qTh,qTl,kTh,kTl,vb,ao);
    conv_gemm<1,2><<<dim3(32,4,B_), 256, 0, stream>>>(wph,wpl,ao,nullptr,bp, nullptr,nullptr,out,x);
}